// Round 4
// baseline (226.357 us; speedup 1.0000x reference)
//
#include <hip/hip_runtime.h>

#define BB 8
#define NN 8192
#define SS 2048
#define DD1 64
#define DD2 128
#define CIN 192
#define CH1 256
#define CH2 128
#define RTOT (BB*NN)   // 65536
#define KCHUNK 512
#define NCHK 4

typedef __attribute__((ext_vector_type(8))) short short8;
typedef __attribute__((ext_vector_type(4))) short shortx4;
typedef __attribute__((ext_vector_type(4))) float floatx4;
typedef __attribute__((ext_vector_type(16))) float floatx16;
typedef __attribute__((ext_vector_type(4))) unsigned uintx4;

__device__ __forceinline__ unsigned short f2bf(float f) {
  unsigned u = __float_as_uint(f);
  u += 0x7fff + ((u >> 16) & 1);   // round-to-nearest-even
  return (unsigned short)(u >> 16);
}
__device__ __forceinline__ float bf2f(unsigned short h) {
  return __uint_as_float(((unsigned)h) << 16);
}

// ---------- fused prep: p2t transpose (2048) + w0T (48) + w1T (32) + stats zero (1) + xq (16) ----------
// xq[B][S/4][16]: per 4-candidate group {x[4], y[4], z[4], |x|^2[4]} — 64 B blocks for
// s_load_dwordx16 in knn3 phase B (wave-uniform candidate coords -> SGPRs, not LDS).
__global__ __launch_bounds__(256) void prep(const float* __restrict__ points2, float* __restrict__ p2t,
                                            const float* __restrict__ w0, unsigned short* __restrict__ w0T,
                                            const float* __restrict__ w1, unsigned short* __restrict__ w1T,
                                            float* __restrict__ stats,
                                            const float* __restrict__ xyz2, float* __restrict__ xq) {
  __shared__ float tile[32][33];
  int blk = blockIdx.x, tid = threadIdx.x;
  int tx = tid & 31, ty = tid >> 5;
  if (blk < 2048) {          // points2 [B][128][S] -> p2t [B][S][128]
    int z = blk >> 8, rem = blk & 255;
    int gy = rem >> 6, gx = rem & 63;
    const float* src = points2 + (size_t)z * DD2 * SS;
    float* dst = p2t + (size_t)z * DD2 * SS;
    int c0 = gx * 32, r0 = gy * 32;
    for (int i = ty; i < 32; i += 8)
      tile[i][tx] = src[(size_t)(r0 + i) * SS + (c0 + tx)];
    __syncthreads();
    for (int i = ty; i < 32; i += 8)
      dst[(size_t)(c0 + i) * DD2 + (r0 + tx)] = tile[tx][i];
  } else if (blk < 2096) {   // w0 [192][256] -> w0T [256][192] bf16
    int r = blk - 2048;
    int gy = r >> 3, gx = r & 7;
    int c0 = gx * 32, r0 = gy * 32;
    for (int i = ty; i < 32; i += 8)
      tile[i][tx] = w0[(size_t)(r0 + i) * CH1 + (c0 + tx)];
    __syncthreads();
    for (int i = ty; i < 32; i += 8)
      w0T[(size_t)(c0 + i) * CIN + (r0 + tx)] = f2bf(tile[tx][i]);
  } else if (blk < 2128) {   // w1 [256][128] -> w1T [128][256] bf16
    int r = blk - 2096;
    int gy = r >> 2, gx = r & 3;
    int c0 = gx * 32, r0 = gy * 32;
    for (int i = ty; i < 32; i += 8)
      tile[i][tx] = w1[(size_t)(r0 + i) * CH2 + (c0 + tx)];
    __syncthreads();
    for (int i = ty; i < 32; i += 8)
      w1T[(size_t)(c0 + i) * CH1 + (r0 + tx)] = f2bf(tile[tx][i]);
  } else if (blk < 2129) {
    for (int i = tid; i < 768; i += 256) stats[i] = 0.f;
  } else {                   // xq build: 16 blocks, one 64B group per thread
    int gid = (blk - 2129) * 256 + tid;      // 0..4095
    int bq = gid >> 9, g = gid & 511;
    const float* src = xyz2 + (size_t)bq * 3 * SS;
    float* dst = xq + (size_t)gid * 16;
    float xx[4], yy[4], zz[4];
#pragma unroll
    for (int j = 0; j < 4; ++j) {
      xx[j] = src[4 * g + j];
      yy[j] = src[SS + 4 * g + j];
      zz[j] = src[2 * SS + 4 * g + j];
    }
#pragma unroll
    for (int j = 0; j < 4; ++j) dst[j] = xx[j];
#pragma unroll
    for (int j = 0; j < 4; ++j) dst[4 + j] = yy[j];
#pragma unroll
    for (int j = 0; j < 4; ++j) dst[8 + j] = zz[j];
#pragma unroll
    for (int j = 0; j < 4; ++j) dst[12 + j] = xx[j] * xx[j] + yy[j] * yy[j] + zz[j] * zz[j];
  }
}

// ---------- fused 3-NN + H0 build ----------
// Phase B: candidate coords via s_load_dwordx16 from xq (constant AS, wave-uniform
//          address) -> SGPRs. Zero LDS traffic in the scan (the old coords-in-LDS
//          broadcast was LDS-BW-bound: 16B/cand/wave x 16 waves = 8.4MB/CU per pass).
//   dist: t = fma(x,qx,w); fma(y,qy,t); fma(z,qz,t); t+pp  (identical rounding to r3).
//   top-4 insert: order-statistic update (1 v_min_u32 + 3 v_med3_u32).
//   NOTE: top-4 slack slot is REQUIRED — truncated-key ties displace the selected
//   POINT (different feature row, O(1) interp error). Top-3/chunk fails (r2).
// Phase C: fp64 rescore of 16 survivors (coords from global xyz2) -> exact ranking.
// Phase E: H0[r,0:64] = p1^T (LDS tile), H0[r,64:192] = interp, float4 gathers.
__global__ __launch_bounds__(256) void knn3_gather(const float* __restrict__ xyz1,
                                                   const float* __restrict__ xyz2,
                                                   const float* __restrict__ points1,
                                                   const float* __restrict__ p2t,
                                                   const float* __restrict__ xq,
                                                   unsigned short* __restrict__ H0) {
  __shared__ __align__(16) float p1t[64][65];
  __shared__ __align__(16) unsigned ck[NCHK][64][4];
  __shared__ int   ldsI[64][3];
  __shared__ float ldsW[64][3];
  int tid = threadIdx.x;
  int r0 = blockIdx.x * 64;
  int b = r0 >> 13;                 // N = 8192
  int n0 = r0 & (NN - 1);
  int row = tid & 63, chk = tid >> 6;
  int n = n0 + row;
  const float* x1 = xyz1 + (size_t)b * 3 * NN;
  float px = x1[n], py = x1[NN + n], pz = x1[2 * NN + n];
  float qx = -2.f * px, qy = -2.f * py, qz = -2.f * pz;
  float pp = px * px + py * py + pz * pz;
  unsigned c0 = 0xFFFFFFFFu, c1 = 0xFFFFFFFFu, c2 = 0xFFFFFFFFu, c3 = 0xFFFFFFFFu;
  // wave-uniform group pointer into xq (constant address space -> s_load)
  const __attribute__((address_space(4))) floatx16* xq4 =
      (const __attribute__((address_space(4))) floatx16*)(xq + (size_t)b * (SS / 4) * 16);
  int gbeg = (int)__builtin_amdgcn_readfirstlane((unsigned)(chk * (KCHUNK / 4)));
#pragma unroll 2
  for (int g = gbeg; g < gbeg + KCHUNK / 4; ++g) {
    floatx16 c = xq4[g];             // s_load_dwordx16: x[4],y[4],z[4],w[4]
#pragma unroll
    for (int e = 0; e < 4; ++e) {
      float t = __builtin_fmaf(c[e], qx, c[12 + e]);
      t = __builtin_fmaf(c[4 + e], qy, t);
      t = __builtin_fmaf(c[8 + e], qz, t);
      t = t + pp;                    // >= 0 (exact-ish |p-x|^2)
      unsigned k = (__float_as_uint(t) & 0xFFFFF800u) | (unsigned)(g * 4 + e);
      // sorted top-4 insert via order statistics: new ci = med3(c[i-1], ci, k)
      unsigned m1, m2, m3;
      asm("v_med3_u32 %0, %1, %2, %3" : "=v"(m1) : "v"(c0), "v"(c1), "v"(k));
      asm("v_med3_u32 %0, %1, %2, %3" : "=v"(m2) : "v"(c1), "v"(c2), "v"(k));
      asm("v_med3_u32 %0, %1, %2, %3" : "=v"(m3) : "v"(c2), "v"(c3), "v"(k));
      c0 = __builtin_elementwise_min(c0, k);   // v_min_u32
      c1 = m1; c2 = m2; c3 = m3;
    }
  }
  *(uintx4*)&ck[chk][row][0] = (uintx4){c0, c1, c2, c3};
  // prefetch the p1 tile into registers: latency hides under the rescore
  floatx4 pv[4];
  const float* p1 = points1 + (size_t)b * DD1 * NN;
#pragma unroll
  for (int t = 0; t < 4; ++t) {
    int i = tid + t * 256;             // 0..1023 = 64ch x 16 float4
    int ch = i >> 4, q = i & 15;
    pv[t] = *(const floatx4*)(p1 + (size_t)ch * NN + n0 + q * 4);
  }
  __syncthreads();
#pragma unroll
  for (int t = 0; t < 4; ++t) {        // p1t stores (all threads)
    int i = tid + t * 256;
    int ch = i >> 4, q = i & 15;
    p1t[ch][q * 4 + 0] = pv[t][0];     // component stores: [64][65] stays 2-way max
    p1t[ch][q * 4 + 1] = pv[t][1];
    p1t[ch][q * 4 + 2] = pv[t][2];
    p1t[ch][q * 4 + 3] = pv[t][3];
  }
  if (tid < 64) {                      // fp64 rescore of 16 survivors
    const float* x2 = xyz2 + (size_t)b * 3 * SS;
    float qpx = x1[n0 + tid], qpy = x1[NN + n0 + tid], qpz = x1[2 * NN + n0 + tid];
    double e0 = 1e300, e1 = 1e300, e2 = 1e300;
    int j0 = 0x7fffffff, j1 = 0x7fffffff, j2 = 0x7fffffff;
#pragma unroll
    for (int c = 0; c < NCHK; ++c)
#pragma unroll
      for (int t = 0; t < 4; ++t) {
        int si = (int)(ck[c][tid][t] & 0x7FFu);
        double dx = (double)x2[si] - (double)qpx;
        double dy = (double)x2[SS + si] - (double)qpy;
        double dz = (double)x2[2 * SS + si] - (double)qpz;
        double d = dx * dx + dy * dy + dz * dz;
        if (d < e2 || (d == e2 && si < j2)) {
          if (d < e1 || (d == e1 && si < j1)) {
            e2 = e1; j2 = j1;
            if (d < e0 || (d == e0 && si < j0)) { e1 = e0; j1 = j0; e0 = d; j0 = si; }
            else                                { e1 = d;  j1 = si; }
          } else { e2 = d; j2 = si; }
        }
      }
    double rr0 = 1.0 / (e0 + 1e-8), rr1 = 1.0 / (e1 + 1e-8), rr2 = 1.0 / (e2 + 1e-8);
    double sw = rr0 + rr1 + rr2;
    ldsI[tid][0] = j0; ldsI[tid][1] = j1; ldsI[tid][2] = j2;
    ldsW[tid][0] = (float)(rr0 / sw);
    ldsW[tid][1] = (float)(rr1 / sw);
    ldsW[tid][2] = (float)(rr2 / sw);
  }
  __syncthreads();
  const float* base = p2t + (size_t)b * SS * DD2;
  unsigned short* Hrow = H0 + (size_t)r0 * CIN;
  for (int i = tid; i < 64 * 48; i += 256) {   // quad-columns: 48 per row
    int rr = i / 48;
    int qc = i - rr * 48;
    floatx4 v;
    if (qc < 16) {
      v[0] = p1t[qc * 4 + 0][rr];
      v[1] = p1t[qc * 4 + 1][rr];
      v[2] = p1t[qc * 4 + 2][rr];
      v[3] = p1t[qc * 4 + 3][rr];
    } else {
      int cc = qc * 4 - DD1;
      floatx4 g0 = *(const floatx4*)(base + (size_t)ldsI[rr][0] * DD2 + cc);
      floatx4 g1 = *(const floatx4*)(base + (size_t)ldsI[rr][1] * DD2 + cc);
      floatx4 g2 = *(const floatx4*)(base + (size_t)ldsI[rr][2] * DD2 + cc);
      float w0 = ldsW[rr][0], w1 = ldsW[rr][1], w2 = ldsW[rr][2];
#pragma unroll
      for (int e = 0; e < 4; ++e)
        v[e] = w0 * g0[e] + w1 * g1[e] + w2 * g2[e];
    }
    shortx4 pk;
#pragma unroll
    for (int e = 0; e < 4; ++e) pk[e] = (short)f2bf(v[e]);
    *(shortx4*)(Hrow + (size_t)rr * CIN + qc * 4) = pk;   // 8B coalesced stores
  }
}

// ---------- bf16 MFMA GEMM + fused column stats (BN batch sums) ----------
// BNFUSE=1: prologue computes BN coeffs from layer-0 sums; A -> relu(a*A+c).
// TRANSP=1: C written transposed as [B][CH2][NN] bf16 (short4 n-runs).
template<int BNFUSE, int K, int TRANSP>
__global__ __launch_bounds__(256) void gemm_mfma(
    const unsigned short* __restrict__ A,
    const unsigned short* __restrict__ BT,
    const float* __restrict__ bias,
    const float* __restrict__ psum, const float* __restrict__ psq,
    const float* __restrict__ pscale, const float* __restrict__ pbias,
    float* __restrict__ osum, float* __restrict__ osq,
    unsigned short* __restrict__ C, int Nc)
{
  __shared__ __align__(16) unsigned short As[128 * 32];
  __shared__ __align__(16) unsigned short Bs[128 * 32];
  __shared__ float sa[BNFUSE ? 256 : 1];
  __shared__ float sc[BNFUSE ? 256 : 1];
  int tid = threadIdx.x;
  int lane = tid & 63, w = tid >> 6;
  int bn = blockIdx.x << 7, bm = blockIdx.y << 7;
  int wm = (w & 1) << 6, wn = (w >> 1) << 6;
  if (BNFUSE) {
    const float invR = 1.0f / RTOT;
    for (int i = tid; i < K; i += 256) {
      float mu = psum[i] * invR;
      float var = psq[i] * invR - mu * mu;
      float aa = pscale[i] * (1.0f / sqrtf(var + 1e-5f));
      sa[i] = aa; sc[i] = pbias[i] - mu * aa;
    }
    __syncthreads();
  }
  floatx4 acc[4][4] = {};   // [mt][nt]
  for (int k0 = 0; k0 < K; k0 += 32) {
    if (!BNFUSE) {
#pragma unroll
      for (int t = 0; t < 2; ++t) {
        int s = (w * 2 + t) * 64 + lane;
        int r = s >> 2;
        int kc = (s & 3) ^ ((r >> 2) & 3);
        const unsigned short* gp = A + (size_t)(bm + r) * K + (k0 + kc * 8);
        __builtin_amdgcn_global_load_lds(
            (const __attribute__((address_space(1))) void*)gp,
            (__attribute__((address_space(3))) void*)(As + (w * 2 + t) * 512),
            16, 0, 0);
      }
    } else {
#pragma unroll
      for (int t = 0; t < 2; ++t) {
        int s = t * 256 + tid;
        int r = s >> 2;
        int kc = (s & 3) ^ ((r >> 2) & 3);
        int kg = k0 + kc * 8;
        short8 raw = *(const short8*)(A + (size_t)(bm + r) * K + kg);
        short8 ov;
#pragma unroll
        for (int j = 0; j < 8; ++j) {
          float v = bf2f((unsigned short)raw[j]);
          v = fmaxf(fmaf(v, sa[kg + j], sc[kg + j]), 0.f);
          ov[j] = (short)f2bf(v);
        }
        *(short8*)(As + s * 8) = ov;
      }
    }
#pragma unroll
    for (int t = 0; t < 2; ++t) {
      int s = (w * 2 + t) * 64 + lane;
      int r = s >> 2;
      int kc = (s & 3) ^ ((r >> 2) & 3);
      const unsigned short* gp = BT + (size_t)(bn + r) * K + (k0 + kc * 8);
      __builtin_amdgcn_global_load_lds(
          (const __attribute__((address_space(1))) void*)gp,
          (__attribute__((address_space(3))) void*)(Bs + (w * 2 + t) * 512),
          16, 0, 0);
    }
    __syncthreads();
    {
      short8 af[4], bfr[4];
      int kcl = lane >> 4;
      int lm = lane & 15;
#pragma unroll
      for (int mt = 0; mt < 4; ++mt) {
        int r = wm + mt * 16 + lm;
        int kp = kcl ^ ((r >> 2) & 3);
        af[mt] = *(const short8*)(As + r * 32 + kp * 8);
      }
#pragma unroll
      for (int nt = 0; nt < 4; ++nt) {
        int r = wn + nt * 16 + lm;
        int kp = kcl ^ ((r >> 2) & 3);
        bfr[nt] = *(const short8*)(Bs + r * 32 + kp * 8);
      }
#pragma unroll
      for (int mt = 0; mt < 4; ++mt)
#pragma unroll
        for (int nt = 0; nt < 4; ++nt)
          acc[mt][nt] = __builtin_amdgcn_mfma_f32_16x16x32_bf16(af[mt], bfr[nt], acc[mt][nt], 0, 0, 0);
    }
    __syncthreads();
  }
  // epilogue: store C (C/D layout col=lane&15, row=(lane>>4)*4+reg) + column stats
  int lm = lane & 15, lq = lane >> 4;
  float bv[4];
#pragma unroll
  for (int nt = 0; nt < 4; ++nt) bv[nt] = bias[bn + wn + nt * 16 + lm];
  float ps[4] = {}, pq[4] = {};
  if (!TRANSP) {
#pragma unroll
    for (int mt = 0; mt < 4; ++mt)
#pragma unroll
      for (int r4 = 0; r4 < 4; ++r4) {
        int rowg = bm + wm + mt * 16 + lq * 4 + r4;
        unsigned short* cp = C + (size_t)rowg * Nc + bn + wn + lm;
#pragma unroll
        for (int nt = 0; nt < 4; ++nt) {
          unsigned short us = f2bf(acc[mt][nt][r4] + bv[nt]);
          cp[nt * 16] = us;
          float vr = bf2f(us);           // stats on the bf16-rounded stored value
          ps[nt] += vr; pq[nt] += vr * vr;
        }
      }
  } else {
    int bq = bm >> 13;                   // batch (bm multiple of 128, 8192%128==0)
    int nbase = (bm & (NN - 1)) + wm + lq * 4;
#pragma unroll
    for (int mt = 0; mt < 4; ++mt) {
      int nn = nbase + mt * 16;
#pragma unroll
      for (int nt = 0; nt < 4; ++nt) {
        int ch = wn + nt * 16 + lm;      // bn == 0 for CH2=128
        shortx4 pk;
#pragma unroll
        for (int r4 = 0; r4 < 4; ++r4) {
          unsigned short us = f2bf(acc[mt][nt][r4] + bv[nt]);
          pk[r4] = (short)us;
          float vr = bf2f(us);
          ps[nt] += vr; pq[nt] += vr * vr;
        }
        *(shortx4*)(C + (((size_t)(bq * CH2 + ch)) << 13) + nn) = pk;
      }
    }
  }
  float* colsum = (float*)As;          // reuse LDS (all waves past last barrier)
  float* colsq  = colsum + 128;
  if (tid < 128) { colsum[tid] = 0.f; colsq[tid] = 0.f; }
  __syncthreads();
#pragma unroll
  for (int nt = 0; nt < 4; ++nt) {
    float s = ps[nt], q = pq[nt];
    s += __shfl_down(s, 32); s += __shfl_down(s, 16);
    q += __shfl_down(q, 32); q += __shfl_down(q, 16);
    if (lq == 0) {
      atomicAdd(&colsum[wn + nt * 16 + lm], s);
      atomicAdd(&colsq [wn + nt * 16 + lm], q);
    }
  }
  __syncthreads();
  if (tid < 128) {
    atomicAdd(&osum[bn + tid], colsum[tid]);
    atomicAdd(&osq [bn + tid], colsq[tid]);
  }
}

// ---------- elementwise BN+ReLU + fp32 convert: zT [B][128][N] bf16 -> out fp32 ----------
__global__ __launch_bounds__(256) void out_cvt(const unsigned short* __restrict__ zT,
                                               const float* __restrict__ sum1, const float* __restrict__ sq1,
                                               const float* __restrict__ s1, const float* __restrict__ bb1,
                                               float* __restrict__ out) {
  size_t gid = (size_t)blockIdx.x * 256 + threadIdx.x;
  size_t base = gid * 8;                       // 8 elems/thread, one n-row segment
  int ch = (int)((base >> 13) & (CH2 - 1));
  const float invR = 1.0f / RTOT;
  float mu = sum1[ch] * invR;
  float var = sq1[ch] * invR - mu * mu;
  float a = s1[ch] * (1.0f / sqrtf(var + 1e-5f));
  float c = bb1[ch] - mu * a;
  short8 z = *(const short8*)(zT + base);
  floatx4 o0, o1;
#pragma unroll
  for (int j = 0; j < 4; ++j) o0[j] = fmaxf(fmaf(bf2f((unsigned short)z[j]), a, c), 0.f);
#pragma unroll
  for (int j = 0; j < 4; ++j) o1[j] = fmaxf(fmaf(bf2f((unsigned short)z[j + 4]), a, c), 0.f);
  *(floatx4*)(out + base) = o0;
  *(floatx4*)(out + base + 4) = o1;
}

extern "C" void kernel_launch(void* const* d_in, const int* in_sizes, int n_in,
                              void* d_out, int out_size, void* d_ws, size_t ws_size,
                              hipStream_t stream) {
  const float* xyz1    = (const float*)d_in[0];
  const float* xyz2    = (const float*)d_in[1];
  const float* points1 = (const float*)d_in[2];
  const float* points2 = (const float*)d_in[3];
  const float* w0  = (const float*)d_in[4];
  const float* cb0 = (const float*)d_in[5];
  const float* s0  = (const float*)d_in[6];
  const float* bb0 = (const float*)d_in[7];
  const float* w1  = (const float*)d_in[8];
  const float* cb1 = (const float*)d_in[9];
  const float* s1  = (const float*)d_in[10];
  const float* bb1 = (const float*)d_in[11];

  float* ws = (float*)d_ws;
  // layout (float units; all 16B-aligned)
  float*          p2t  = ws;                               // 2,097,152
  unsigned short* H0   = (unsigned short*)(ws + 2097152);  // R*192 bf16
  unsigned short* Z0   = (unsigned short*)(ws + 8388608);  // R*256 bf16
  unsigned short* zT   = (unsigned short*)(ws + 16777216); // R*128 bf16, [B][128][N]
  unsigned short* w0T  = (unsigned short*)(ws + 20971520); //    24,576
  unsigned short* w1T  = (unsigned short*)(ws + 20996096); //    16,384
  float*          stats= ws + 21012480;                    //       768
  // xq aliases the Z0 region (dead until gemm1): 65,536 floats, 64B-aligned
  float*          xq   = ws + 8388608;

  float* sum0 = stats;        float* sq0 = stats + 256;
  float* sum1 = stats + 512;  float* sq1 = stats + 640;

  // 1: transposes + weight cvt + stats zero + xq build (all independent)
  prep<<<2145, 256, 0, stream>>>(points2, p2t, w0, w0T, w1, w1T, stats, xyz2, xq);

  // 2: 3-NN + interp + H0 build (fused)
  knn3_gather<<<RTOT / 64, 256, 0, stream>>>(xyz1, xyz2, points1, p2t, xq, H0);

  // 3: Z0 = H0 @ W0 + b0, + column sums for BN0
  gemm_mfma<0, CIN, 0><<<dim3(CH1 / 128, RTOT / 128), 256, 0, stream>>>(
      H0, w0T, cb0, nullptr, nullptr, nullptr, nullptr, sum0, sq0, Z0, CH1);

  // 4: zT = (relu(BN0(Z0)) @ W1 + b1)^T  (BN coeffs in prologue), + sums for BN1
  gemm_mfma<1, CH1, 1><<<dim3(CH2 / 128, RTOT / 128), 256, 0, stream>>>(
      Z0, w1T, cb1, sum0, sq0, s0, bb0, sum1, sq1, zT, CH2);

  // 5: out = relu(BN1(zT)) as fp32, pure elementwise
  out_cvt<<<RTOT * CH2 / 8 / 256, 256, 0, stream>>>(
      zT, sum1, sq1, s1, bb1, (float*)d_out);
}

// Round 5
// 212.524 us; speedup vs baseline: 1.0651x; 1.0651x over previous
//
#include <hip/hip_runtime.h>

#define BB 8
#define NN 8192
#define SS 2048
#define DD1 64
#define DD2 128
#define CIN 192
#define CH1 256
#define CH2 128
#define RTOT (BB*NN)   // 65536
#define KCHUNK 256
#define NCHK 8

typedef __attribute__((ext_vector_type(8))) short short8;
typedef __attribute__((ext_vector_type(4))) short shortx4;
typedef __attribute__((ext_vector_type(4))) float floatx4;
typedef __attribute__((ext_vector_type(4))) unsigned uintx4;

__device__ __forceinline__ unsigned short f2bf(float f) {
  unsigned u = __float_as_uint(f);
  u += 0x7fff + ((u >> 16) & 1);   // round-to-nearest-even
  return (unsigned short)(u >> 16);
}
__device__ __forceinline__ float bf2f(unsigned short h) {
  return __uint_as_float(((unsigned)h) << 16);
}

// ---------- fused prep: p2t transpose (2048 blks) + w0T (48) + w1T (32) + stats zero (1) ----------
__global__ __launch_bounds__(256) void prep(const float* __restrict__ points2, float* __restrict__ p2t,
                                            const float* __restrict__ w0, unsigned short* __restrict__ w0T,
                                            const float* __restrict__ w1, unsigned short* __restrict__ w1T,
                                            float* __restrict__ stats) {
  __shared__ float tile[32][33];
  int blk = blockIdx.x, tid = threadIdx.x;
  int tx = tid & 31, ty = tid >> 5;
  if (blk < 2048) {          // points2 [B][128][S] -> p2t [B][S][128]
    int z = blk >> 8, rem = blk & 255;
    int gy = rem >> 6, gx = rem & 63;
    const float* src = points2 + (size_t)z * DD2 * SS;
    float* dst = p2t + (size_t)z * DD2 * SS;
    int c0 = gx * 32, r0 = gy * 32;
    for (int i = ty; i < 32; i += 8)
      tile[i][tx] = src[(size_t)(r0 + i) * SS + (c0 + tx)];
    __syncthreads();
    for (int i = ty; i < 32; i += 8)
      dst[(size_t)(c0 + i) * DD2 + (r0 + tx)] = tile[tx][i];
  } else if (blk < 2096) {   // w0 [192][256] -> w0T [256][192] bf16
    int r = blk - 2048;
    int gy = r >> 3, gx = r & 7;
    int c0 = gx * 32, r0 = gy * 32;
    for (int i = ty; i < 32; i += 8)
      tile[i][tx] = w0[(size_t)(r0 + i) * CH1 + (c0 + tx)];
    __syncthreads();
    for (int i = ty; i < 32; i += 8)
      w0T[(size_t)(c0 + i) * CIN + (r0 + tx)] = f2bf(tile[tx][i]);
  } else if (blk < 2128) {   // w1 [256][128] -> w1T [128][256] bf16
    int r = blk - 2096;
    int gy = r >> 2, gx = r & 3;
    int c0 = gx * 32, r0 = gy * 32;
    for (int i = ty; i < 32; i += 8)
      tile[i][tx] = w1[(size_t)(r0 + i) * CH2 + (c0 + tx)];
    __syncthreads();
    for (int i = ty; i < 32; i += 8)
      w1T[(size_t)(c0 + i) * CH1 + (r0 + tx)] = f2bf(tile[tx][i]);
  } else {
    for (int i = tid; i < 768; i += 256) stats[i] = 0.f;
  }
}

// ---------- fused 3-NN + H0 build (512 threads = 8 waves/block) ----------
// Occupancy lever: r3 ran 4 waves/block at 30% occ, VALU-stall-bound (static model
// ~25us vs 62us measured). 8 waves/block + LDS trimmed to exactly 40960B keeps
// 4 blocks/CU -> 32 waves/CU ceiling (was 16). NCHK=8 x KCHUNK=256 (chunk-top-4 on
// 256-cand chunks is strictly safer than 512: fewer near-tie displacements).
// Phase B: coords broadcast from LDS (r4 s_load path REGRESSED: latency+sL1 thrash).
//   top-4 insert: 1 v_min_u32 + 3 v_med3_u32. Top-4 slack REQUIRED (r2: top-3 fails —
//   truncated-key ties displace the selected POINT, O(1) feature error).
// Phase C: fp64 rescore of 32 survivors -> exact reference ranking + weights.
//   ldsI/ldsW alias ck's region; writes separated from ck reads by a barrier.
// Phase E: H0[r,0:64] = p1^T (LDS tile), H0[r,64:192] = interp, float4 gathers.
__global__ __launch_bounds__(512) void knn3_gather(const float* __restrict__ xyz1,
                                                   const float* __restrict__ xyz2,
                                                   const float* __restrict__ points1,
                                                   const float* __restrict__ p2t,
                                                   unsigned short* __restrict__ H0) {
  __shared__ __align__(16) union LU {
    float coords[4][SS];     // 32 KB: x,y,z,|x|^2 — phases A-C
    float p1t[64][65];       // 16.6 KB, phases D-E (coords dead)
  } u;
  __shared__ __align__(16) unsigned ck[NCHK][64][4];   // 8 KB; tail reused post-rescore
  int* ldsI   = (int*)&ck[0][0][0];          // [64][3] — aliases ck, written after barrier
  float* ldsW = (float*)&ck[0][0][0] + 192;  // [64][3]
  int tid = threadIdx.x;
  int r0 = blockIdx.x * 64;
  int b = r0 >> 13;                 // N = 8192
  int n0 = r0 & (NN - 1);
  const float* x2 = xyz2 + (size_t)b * 3 * SS;
  for (int i = tid; i < SS; i += 512) {
    float xv = x2[i], yv = x2[SS + i], zv = x2[2 * SS + i];
    u.coords[0][i] = xv;
    u.coords[1][i] = yv;
    u.coords[2][i] = zv;
    u.coords[3][i] = xv * xv + yv * yv + zv * zv;
  }
  __syncthreads();
  int row = tid & 63, chk = tid >> 6;   // chunk wave-uniform -> LDS broadcasts
  int n = n0 + row;
  const float* x1 = xyz1 + (size_t)b * 3 * NN;
  float px = x1[n], py = x1[NN + n], pz = x1[2 * NN + n];
  float qx = -2.f * px, qy = -2.f * py, qz = -2.f * pz;
  float pp = px * px + py * py + pz * pz;
  floatx4 qx4 = {qx, qx, qx, qx}, qy4 = {qy, qy, qy, qy};
  floatx4 qz4 = {qz, qz, qz, qz}, pp4 = {pp, pp, pp, pp};
  unsigned c0 = 0xFFFFFFFFu, c1 = 0xFFFFFFFFu, c2 = 0xFFFFFFFFu, c3 = 0xFFFFFFFFu;
  int sbeg = (int)__builtin_amdgcn_readfirstlane((unsigned)(chk * KCHUNK));
#pragma unroll 2
  for (int s8 = sbeg; s8 < sbeg + KCHUNK; s8 += 8) {
#pragma unroll
    for (int p = 0; p < 2; ++p) {
      floatx4 xv = *(const floatx4*)&u.coords[0][s8 + 4 * p];
      floatx4 yv = *(const floatx4*)&u.coords[1][s8 + 4 * p];
      floatx4 zv = *(const floatx4*)&u.coords[2][s8 + 4 * p];
      floatx4 wv = *(const floatx4*)&u.coords[3][s8 + 4 * p];
      floatx4 d = xv * qx4 + wv;        // fma
      d = yv * qy4 + d;                 // fma
      d = zv * qz4 + d;                 // fma
      d = d + pp4;                      // add; d >= 0 (exact-ish |p-x|^2)
#pragma unroll
      for (int e = 0; e < 4; ++e) {
        unsigned k = (__float_as_uint(d[e]) & 0xFFFFF800u) | (unsigned)(s8 + 4 * p + e);
        // sorted top-4 insert via order statistics: new ci = med3(c[i-1], ci, k)
        unsigned m1, m2, m3;
        asm("v_med3_u32 %0, %1, %2, %3" : "=v"(m1) : "v"(c0), "v"(c1), "v"(k));
        asm("v_med3_u32 %0, %1, %2, %3" : "=v"(m2) : "v"(c1), "v"(c2), "v"(k));
        asm("v_med3_u32 %0, %1, %2, %3" : "=v"(m3) : "v"(c2), "v"(c3), "v"(k));
        c0 = __builtin_elementwise_min(c0, k);   // v_min_u32
        c1 = m1; c2 = m2; c3 = m3;
      }
    }
  }
  *(uintx4*)&ck[chk][row][0] = (uintx4){c0, c1, c2, c3};
  // prefetch the p1 tile into registers: latency hides under the rescore
  floatx4 pv[2];
  const float* p1 = points1 + (size_t)b * DD1 * NN;
#pragma unroll
  for (int t = 0; t < 2; ++t) {
    int i = tid + t * 512;             // 0..1023 = 64ch x 16 float4
    int ch = i >> 4, q = i & 15;
    pv[t] = *(const floatx4*)(p1 + (size_t)ch * NN + n0 + q * 4);
  }
  __syncthreads();
  // rescore into registers (reads u.coords + ck; no LDS writes yet)
  int j0, j1, j2; float fw0, fw1, fw2;
  if (tid < 64) {
    float qpx = x1[n0 + tid], qpy = x1[NN + n0 + tid], qpz = x1[2 * NN + n0 + tid];
    double e0 = 1e300, e1 = 1e300, e2 = 1e300;
    j0 = 0x7fffffff; j1 = 0x7fffffff; j2 = 0x7fffffff;
#pragma unroll
    for (int c = 0; c < NCHK; ++c)
#pragma unroll
      for (int t = 0; t < 4; ++t) {
        int si = (int)(ck[c][tid][t] & 0x7FFu);
        double dx = (double)u.coords[0][si] - (double)qpx;
        double dy = (double)u.coords[1][si] - (double)qpy;
        double dz = (double)u.coords[2][si] - (double)qpz;
        double d = dx * dx + dy * dy + dz * dz;
        if (d < e2 || (d == e2 && si < j2)) {
          if (d < e1 || (d == e1 && si < j1)) {
            e2 = e1; j2 = j1;
            if (d < e0 || (d == e0 && si < j0)) { e1 = e0; j1 = j0; e0 = d; j0 = si; }
            else                                { e1 = d;  j1 = si; }
          } else { e2 = d; j2 = si; }
        }
      }
    double rr0 = 1.0 / (e0 + 1e-8), rr1 = 1.0 / (e1 + 1e-8), rr2 = 1.0 / (e2 + 1e-8);
    double sw = rr0 + rr1 + rr2;
    fw0 = (float)(rr0 / sw); fw1 = (float)(rr1 / sw); fw2 = (float)(rr2 / sw);
  }
  __syncthreads();                      // all ck/coords reads done; aliased regions now writable
#pragma unroll
  for (int t = 0; t < 2; ++t) {         // p1t stores (coords region dead)
    int i = tid + t * 512;
    int ch = i >> 4, q = i & 15;
    u.p1t[ch][q * 4 + 0] = pv[t][0];    // component stores: [64][65] stays 2-way max
    u.p1t[ch][q * 4 + 1] = pv[t][1];
    u.p1t[ch][q * 4 + 2] = pv[t][2];
    u.p1t[ch][q * 4 + 3] = pv[t][3];
  }
  if (tid < 64) {                       // ldsI/ldsW into ck's (consumed) region
    ldsI[tid * 3 + 0] = j0; ldsI[tid * 3 + 1] = j1; ldsI[tid * 3 + 2] = j2;
    ldsW[tid * 3 + 0] = fw0; ldsW[tid * 3 + 1] = fw1; ldsW[tid * 3 + 2] = fw2;
  }
  __syncthreads();
  const float* base = p2t + (size_t)b * SS * DD2;
  unsigned short* Hrow = H0 + (size_t)r0 * CIN;
  for (int i = tid; i < 64 * 48; i += 512) {   // quad-columns: 48 per row
    int rr = i / 48;
    int qc = i - rr * 48;
    floatx4 v;
    if (qc < 16) {
      v[0] = u.p1t[qc * 4 + 0][rr];
      v[1] = u.p1t[qc * 4 + 1][rr];
      v[2] = u.p1t[qc * 4 + 2][rr];
      v[3] = u.p1t[qc * 4 + 3][rr];
    } else {
      int cc = qc * 4 - DD1;
      floatx4 g0 = *(const floatx4*)(base + (size_t)ldsI[rr * 3 + 0] * DD2 + cc);
      floatx4 g1 = *(const floatx4*)(base + (size_t)ldsI[rr * 3 + 1] * DD2 + cc);
      floatx4 g2 = *(const floatx4*)(base + (size_t)ldsI[rr * 3 + 2] * DD2 + cc);
      float w0 = ldsW[rr * 3 + 0], w1 = ldsW[rr * 3 + 1], w2 = ldsW[rr * 3 + 2];
#pragma unroll
      for (int e = 0; e < 4; ++e)
        v[e] = w0 * g0[e] + w1 * g1[e] + w2 * g2[e];
    }
    shortx4 pk;
#pragma unroll
    for (int e = 0; e < 4; ++e) pk[e] = (short)f2bf(v[e]);
    *(shortx4*)(Hrow + (size_t)rr * CIN + qc * 4) = pk;   // 8B coalesced stores
  }
}

// ---------- bf16 MFMA GEMM + fused column stats (BN batch sums) ----------
// BNFUSE=1: prologue computes BN coeffs from layer-0 sums; A -> relu(a*A+c).
// TRANSP=1: C written transposed as [B][CH2][NN] bf16 (short4 n-runs).
template<int BNFUSE, int K, int TRANSP>
__global__ __launch_bounds__(256) void gemm_mfma(
    const unsigned short* __restrict__ A,
    const unsigned short* __restrict__ BT,
    const float* __restrict__ bias,
    const float* __restrict__ psum, const float* __restrict__ psq,
    const float* __restrict__ pscale, const float* __restrict__ pbias,
    float* __restrict__ osum, float* __restrict__ osq,
    unsigned short* __restrict__ C, int Nc)
{
  __shared__ __align__(16) unsigned short As[128 * 32];
  __shared__ __align__(16) unsigned short Bs[128 * 32];
  __shared__ float sa[BNFUSE ? 256 : 1];
  __shared__ float sc[BNFUSE ? 256 : 1];
  int tid = threadIdx.x;
  int lane = tid & 63, w = tid >> 6;
  int bn = blockIdx.x << 7, bm = blockIdx.y << 7;
  int wm = (w & 1) << 6, wn = (w >> 1) << 6;
  if (BNFUSE) {
    const float invR = 1.0f / RTOT;
    for (int i = tid; i < K; i += 256) {
      float mu = psum[i] * invR;
      float var = psq[i] * invR - mu * mu;
      float aa = pscale[i] * (1.0f / sqrtf(var + 1e-5f));
      sa[i] = aa; sc[i] = pbias[i] - mu * aa;
    }
    __syncthreads();
  }
  floatx4 acc[4][4] = {};   // [mt][nt]
  for (int k0 = 0; k0 < K; k0 += 32) {
    if (!BNFUSE) {
#pragma unroll
      for (int t = 0; t < 2; ++t) {
        int s = (w * 2 + t) * 64 + lane;
        int r = s >> 2;
        int kc = (s & 3) ^ ((r >> 2) & 3);
        const unsigned short* gp = A + (size_t)(bm + r) * K + (k0 + kc * 8);
        __builtin_amdgcn_global_load_lds(
            (const __attribute__((address_space(1))) void*)gp,
            (__attribute__((address_space(3))) void*)(As + (w * 2 + t) * 512),
            16, 0, 0);
      }
    } else {
#pragma unroll
      for (int t = 0; t < 2; ++t) {
        int s = t * 256 + tid;
        int r = s >> 2;
        int kc = (s & 3) ^ ((r >> 2) & 3);
        int kg = k0 + kc * 8;
        short8 raw = *(const short8*)(A + (size_t)(bm + r) * K + kg);
        short8 ov;
#pragma unroll
        for (int j = 0; j < 8; ++j) {
          float v = bf2f((unsigned short)raw[j]);
          v = fmaxf(fmaf(v, sa[kg + j], sc[kg + j]), 0.f);
          ov[j] = (short)f2bf(v);
        }
        *(short8*)(As + s * 8) = ov;
      }
    }
#pragma unroll
    for (int t = 0; t < 2; ++t) {
      int s = (w * 2 + t) * 64 + lane;
      int r = s >> 2;
      int kc = (s & 3) ^ ((r >> 2) & 3);
      const unsigned short* gp = BT + (size_t)(bn + r) * K + (k0 + kc * 8);
      __builtin_amdgcn_global_load_lds(
          (const __attribute__((address_space(1))) void*)gp,
          (__attribute__((address_space(3))) void*)(Bs + (w * 2 + t) * 512),
          16, 0, 0);
    }
    __syncthreads();
    {
      short8 af[4], bfr[4];
      int kcl = lane >> 4;
      int lm = lane & 15;
#pragma unroll
      for (int mt = 0; mt < 4; ++mt) {
        int r = wm + mt * 16 + lm;
        int kp = kcl ^ ((r >> 2) & 3);
        af[mt] = *(const short8*)(As + r * 32 + kp * 8);
      }
#pragma unroll
      for (int nt = 0; nt < 4; ++nt) {
        int r = wn + nt * 16 + lm;
        int kp = kcl ^ ((r >> 2) & 3);
        bfr[nt] = *(const short8*)(Bs + r * 32 + kp * 8);
      }
#pragma unroll
      for (int mt = 0; mt < 4; ++mt)
#pragma unroll
        for (int nt = 0; nt < 4; ++nt)
          acc[mt][nt] = __builtin_amdgcn_mfma_f32_16x16x32_bf16(af[mt], bfr[nt], acc[mt][nt], 0, 0, 0);
    }
    __syncthreads();
  }
  // epilogue: store C (C/D layout col=lane&15, row=(lane>>4)*4+reg) + column stats
  int lm = lane & 15, lq = lane >> 4;
  float bv[4];
#pragma unroll
  for (int nt = 0; nt < 4; ++nt) bv[nt] = bias[bn + wn + nt * 16 + lm];
  float ps[4] = {}, pq[4] = {};
  if (!TRANSP) {
#pragma unroll
    for (int mt = 0; mt < 4; ++mt)
#pragma unroll
      for (int r4 = 0; r4 < 4; ++r4) {
        int rowg = bm + wm + mt * 16 + lq * 4 + r4;
        unsigned short* cp = C + (size_t)rowg * Nc + bn + wn + lm;
#pragma unroll
        for (int nt = 0; nt < 4; ++nt) {
          unsigned short us = f2bf(acc[mt][nt][r4] + bv[nt]);
          cp[nt * 16] = us;
          float vr = bf2f(us);           // stats on the bf16-rounded stored value
          ps[nt] += vr; pq[nt] += vr * vr;
        }
      }
  } else {
    int bq = bm >> 13;                   // batch (bm multiple of 128, 8192%128==0)
    int nbase = (bm & (NN - 1)) + wm + lq * 4;
#pragma unroll
    for (int mt = 0; mt < 4; ++mt) {
      int nn = nbase + mt * 16;
#pragma unroll
      for (int nt = 0; nt < 4; ++nt) {
        int ch = wn + nt * 16 + lm;      // bn == 0 for CH2=128
        shortx4 pk;
#pragma unroll
        for (int r4 = 0; r4 < 4; ++r4) {
          unsigned short us = f2bf(acc[mt][nt][r4] + bv[nt]);
          pk[r4] = (short)us;
          float vr = bf2f(us);
          ps[nt] += vr; pq[nt] += vr * vr;
        }
        *(shortx4*)(C + (((size_t)(bq * CH2 + ch)) << 13) + nn) = pk;
      }
    }
  }
  float* colsum = (float*)As;          // reuse LDS (all waves past last barrier)
  float* colsq  = colsum + 128;
  if (tid < 128) { colsum[tid] = 0.f; colsq[tid] = 0.f; }
  __syncthreads();
#pragma unroll
  for (int nt = 0; nt < 4; ++nt) {
    float s = ps[nt], q = pq[nt];
    s += __shfl_down(s, 32); s += __shfl_down(s, 16);
    q += __shfl_down(q, 32); q += __shfl_down(q, 16);
    if (lq == 0) {
      atomicAdd(&colsum[wn + nt * 16 + lm], s);
      atomicAdd(&colsq [wn + nt * 16 + lm], q);
    }
  }
  __syncthreads();
  if (tid < 128) {
    atomicAdd(&osum[bn + tid], colsum[tid]);
    atomicAdd(&osq [bn + tid], colsq[tid]);
  }
}

// ---------- elementwise BN+ReLU + fp32 convert: zT [B][128][N] bf16 -> out fp32 ----------
__global__ __launch_bounds__(256) void out_cvt(const unsigned short* __restrict__ zT,
                                               const float* __restrict__ sum1, const float* __restrict__ sq1,
                                               const float* __restrict__ s1, const float* __restrict__ bb1,
                                               float* __restrict__ out) {
  size_t gid = (size_t)blockIdx.x * 256 + threadIdx.x;
  size_t base = gid * 8;                       // 8 elems/thread, one n-row segment
  int ch = (int)((base >> 13) & (CH2 - 1));
  const float invR = 1.0f / RTOT;
  float mu = sum1[ch] * invR;
  float var = sq1[ch] * invR - mu * mu;
  float a = s1[ch] * (1.0f / sqrtf(var + 1e-5f));
  float c = bb1[ch] - mu * a;
  short8 z = *(const short8*)(zT + base);
  floatx4 o0, o1;
#pragma unroll
  for (int j = 0; j < 4; ++j) o0[j] = fmaxf(fmaf(bf2f((unsigned short)z[j]), a, c), 0.f);
#pragma unroll
  for (int j = 0; j < 4; ++j) o1[j] = fmaxf(fmaf(bf2f((unsigned short)z[j + 4]), a, c), 0.f);
  *(floatx4*)(out + base) = o0;
  *(floatx4*)(out + base + 4) = o1;
}

extern "C" void kernel_launch(void* const* d_in, const int* in_sizes, int n_in,
                              void* d_out, int out_size, void* d_ws, size_t ws_size,
                              hipStream_t stream) {
  const float* xyz1    = (const float*)d_in[0];
  const float* xyz2    = (const float*)d_in[1];
  const float* points1 = (const float*)d_in[2];
  const float* points2 = (const float*)d_in[3];
  const float* w0  = (const float*)d_in[4];
  const float* cb0 = (const float*)d_in[5];
  const float* s0  = (const float*)d_in[6];
  const float* bb0 = (const float*)d_in[7];
  const float* w1  = (const float*)d_in[8];
  const float* cb1 = (const float*)d_in[9];
  const float* s1  = (const float*)d_in[10];
  const float* bb1 = (const float*)d_in[11];

  float* ws = (float*)d_ws;
  // layout (float units; all 16B-aligned)
  float*          p2t  = ws;                               // 2,097,152
  unsigned short* H0   = (unsigned short*)(ws + 2097152);  // R*192 bf16
  unsigned short* Z0   = (unsigned short*)(ws + 8388608);  // R*256 bf16
  unsigned short* zT   = (unsigned short*)(ws + 16777216); // R*128 bf16, [B][128][N]
  unsigned short* w0T  = (unsigned short*)(ws + 20971520); //    24,576
  unsigned short* w1T  = (unsigned short*)(ws + 20996096); //    16,384
  float*          stats= ws + 21012480;                    //       768

  float* sum0 = stats;        float* sq0 = stats + 256;
  float* sum1 = stats + 512;  float* sq1 = stats + 640;

  // 1: transposes + weight cvt + stats zero (all independent)
  prep<<<2129, 256, 0, stream>>>(points2, p2t, w0, w0T, w1, w1T, stats);

  // 2: 3-NN + interp + H0 build (fused), 8 waves/block
  knn3_gather<<<RTOT / 64, 512, 0, stream>>>(xyz1, xyz2, points1, p2t, H0);

  // 3: Z0 = H0 @ W0 + b0, + column sums for BN0
  gemm_mfma<0, CIN, 0><<<dim3(CH1 / 128, RTOT / 128), 256, 0, stream>>>(
      H0, w0T, cb0, nullptr, nullptr, nullptr, nullptr, sum0, sq0, Z0, CH1);

  // 4: zT = (relu(BN0(Z0)) @ W1 + b1)^T  (BN coeffs in prologue), + sums for BN1
  gemm_mfma<1, CH1, 1><<<dim3(CH2 / 128, RTOT / 128), 256, 0, stream>>>(
      Z0, w1T, cb1, sum0, sq0, s0, bb0, sum1, sq1, zT, CH2);

  // 5: out = relu(BN1(zT)) as fp32, pure elementwise
  out_cvt<<<RTOT * CH2 / 8 / 256, 256, 0, stream>>>(
      zT, sum1, sq1, s1, bb1, (float*)d_out);
}